// Round 7
// baseline (489.128 us; speedup 1.0000x reference)
//
#include <hip/hip_runtime.h>

#define DEV __device__ __forceinline__

typedef __attribute__((ext_vector_type(8))) short short8;
typedef __attribute__((ext_vector_type(4))) float f32x4;
typedef __attribute__((ext_vector_type(4))) unsigned short ushort4_t;
typedef __attribute__((ext_vector_type(4))) unsigned int uint4_t;

namespace {
constexpr int D_ = 256, C_ = 10, T_ = 15, H_ = 5, ENC_ = 64, L_ = 16;
constexpr int NS_ = 2048, NQ_ = 32768;
constexpr int P_ = 60240, SW_ = 57600, SB_ = 225, LF_ = 2400;
constexpr int FEAT_ = 128;
constexpr int G_ = 75;                      // H*T groups
constexpr int WGB_ = 16384;                 // bytes per group W-image

// workspace layout (in floats)
constexpr size_t OFF_H2   = 0;                                  // 5*2048*64
constexpr size_t OFF_PVEC = OFF_H2 + (size_t)H_*NS_*ENC_;
constexpr size_t OFF_TMP  = OFF_PVEC + (size_t)H_*FEAT_;
constexpr size_t OFF_SB   = OFF_TMP + 8;
constexpr size_t OFF_LRAW = OFF_SB + (size_t)H_*T_*T_ + 16;
constexpr size_t OFF_TRAW = OFF_LRAW + (size_t)H_*T_*L_*C_;
constexpr size_t OFF_SL   = OFF_TRAW + (size_t)H_*T_;
constexpr size_t OFF_WBF  = OFF_SL + (size_t)H_*T_*L_*C_;       // 75*16384B
constexpr size_t OFF_SLA  = OFF_WBF + (size_t)G_*WGB_/4;        // 75*1024B
constexpr size_t WS_NEED_FLOATS = OFF_SLA + (size_t)G_*1024/4;
} // namespace

DEV float wave_sum(float v) {
  #pragma unroll
  for (int o = 32; o; o >>= 1) v += __shfl_xor(v, o, 64);
  return v;
}
DEV float gelu_exact(float x) { return 0.5f * x * (1.f + erff(x * 0.70710678118654752f)); }
DEV unsigned short f2bf(float x) {            // RNE bf16
  unsigned u = __float_as_uint(x);
  return (unsigned short)((u + 0x7FFFu + ((u >> 16) & 1u)) >> 16);
}
DEV float bf2f(unsigned short b) { return __uint_as_float(((unsigned)b) << 16); }
DEV unsigned cvt_pk_bf16(float lo, float hi) {
  unsigned d;
  asm("v_cvt_pk_bf16_f32 %0, %1, %2" : "=v"(d) : "v"(lo), "v"(hi));
  return d;
}
// async global -> LDS DMA, 16B per lane; lds dest = uniform base + lane*16
DEV void gload16(const char* g, char* l) {
  __builtin_amdgcn_global_load_lds(
      (const __attribute__((address_space(1))) void*)g,
      (__attribute__((address_space(3))) void*)l, 16, 0, 0);
}

// ---------------- fused encoder: h2 = enc2(enc1(X)), h1 lives in LDS ----------------
__global__ __launch_bounds__(256) void enc12_kernel(
    const float* __restrict__ Xbase,
    const float* __restrict__ W1, const float* __restrict__ B1,
    const float* __restrict__ G1, const float* __restrict__ Be1,
    const float* __restrict__ W2, const float* __restrict__ B2,
    const float* __restrict__ G2, const float* __restrict__ Be2,
    float* __restrict__ Out)
{
  __shared__ float xs[4][4][ENC_];     // [wave][row][col] = 4 KB
  const int h = blockIdx.y;
  const int lane = threadIdx.x & 63;
  const int wv = threadIdx.x >> 6;
  const int row0 = blockIdx.x * 16 + wv * 4;

  { // ---- enc1: K=256 from global ----
    constexpr int K = 256;
    const float* __restrict__ X = Xbase + (size_t)row0 * K;
    const float* __restrict__ wc = W1 + (size_t)h * K * ENC_ + lane;
    float a0 = 0.f, a1 = 0.f, a2 = 0.f, a3 = 0.f;
    #pragma unroll 4
    for (int k = 0; k < K; ++k) {
      const float wkl = wc[(size_t)k * ENC_];
      a0 = fmaf(X[k],       wkl, a0);
      a1 = fmaf(X[K + k],   wkl, a1);
      a2 = fmaf(X[2*K + k], wkl, a2);
      a3 = fmaf(X[3*K + k], wkl, a3);
    }
    const float bb = B1[h*ENC_ + lane];
    const float gg = G1[h*ENC_ + lane], be = Be1[h*ENC_ + lane];
    float acc[4] = {a0 + bb, a1 + bb, a2 + bb, a3 + bb};
    #pragma unroll
    for (int r = 0; r < 4; ++r) {
      const float m = wave_sum(acc[r]) * (1.f / ENC_);
      const float d = acc[r] - m;
      const float var = wave_sum(d * d) * (1.f / ENC_);
      const float y = d * rsqrtf(var + 1e-5f) * gg + be;
      xs[wv][r][lane] = gelu_exact(y);
    }
  }
  __syncthreads();
  { // ---- enc2: K=64 from LDS (wave-local rows) ----
    constexpr int K = 64;
    const float* __restrict__ wc = W2 + (size_t)h * K * ENC_ + lane;
    float a0 = 0.f, a1 = 0.f, a2 = 0.f, a3 = 0.f;
    #pragma unroll 4
    for (int k = 0; k < K; ++k) {
      const float wkl = wc[(size_t)k * ENC_];
      a0 = fmaf(xs[wv][0][k], wkl, a0);
      a1 = fmaf(xs[wv][1][k], wkl, a1);
      a2 = fmaf(xs[wv][2][k], wkl, a2);
      a3 = fmaf(xs[wv][3][k], wkl, a3);
    }
    const float bb = B2[h*ENC_ + lane];
    const float gg = G2[h*ENC_ + lane], be = Be2[h*ENC_ + lane];
    float acc[4] = {a0 + bb, a1 + bb, a2 + bb, a3 + bb};
    #pragma unroll
    for (int r = 0; r < 4; ++r) {
      const float m = wave_sum(acc[r]) * (1.f / ENC_);
      const float d = acc[r] - m;
      const float var = wave_sum(d * d) * (1.f / ENC_);
      const float y = d * rsqrtf(var + 1e-5f) * gg + be;
      Out[((size_t)h * NS_ + row0 + r) * ENC_ + lane] = gelu_exact(y);
    }
  }
}

// ---------------- fused ctx (mean over support) + pvec, 128 threads/head ----------------
__global__ __launch_bounds__(128) void ctxpvec_kernel(
    const float* __restrict__ h2, const float* __restrict__ temperature,
    const float* __restrict__ w1, const float* __restrict__ b1,
    const float* __restrict__ g, const float* __restrict__ b,
    float* __restrict__ pvec, float* __restrict__ tmp)
{
  __shared__ float red[128];
  __shared__ float ctxl[ENC_];
  __shared__ float sred[2];
  const int h = blockIdx.x, tid = threadIdx.x;
  const int e = tid & 63, part = tid >> 6;
  float s = 0.f;
  for (int n = part; n < NS_; n += 2) s += h2[((size_t)h * NS_ + n) * ENC_ + e];
  red[tid] = s;
  __syncthreads();
  if (part == 0) ctxl[e] = (red[e] + red[64 + e]) * (1.f / NS_);
  if (h == 0 && tid == 0) {
    const float t = fminf(fmaxf(temperature[0], 0.1f), 2.0f);
    tmp[0] = t; tmp[1] = 1.f / t;
  }
  __syncthreads();
  const int j = tid;
  float acc = b1[h * FEAT_ + j];
  #pragma unroll 4
  for (int e2 = 0; e2 < ENC_; ++e2)
    acc = fmaf(ctxl[e2], w1[((size_t)h * ENC_ + e2) * FEAT_ + j], acc);
  const int lane = j & 63, wvv = j >> 6;
  const float ps = wave_sum(acc);
  if (lane == 0) sred[wvv] = ps;
  __syncthreads();
  const float m = (sred[0] + sred[1]) * (1.f / FEAT_);
  const float d = acc - m;
  const float vs = wave_sum(d * d);
  __syncthreads();
  if (lane == 0) sred[wvv] = vs;
  __syncthreads();
  const float var = (sred[0] + sred[1]) * (1.f / FEAT_);
  const float y = d * rsqrtf(var + 1e-5f) * g[h * FEAT_ + j] + b[h * FEAT_ + j];
  pvec[h * FEAT_ + j] = gelu_exact(y);
}

// ---------------- params = tanh(p @ pg_w2 + pg_b2)*2 → W bf16 hi/lo image + sb/leaf/tree ----------------
__global__ __launch_bounds__(256) void params_kernel(
    const float* __restrict__ pvec, const float* __restrict__ w2,
    const float* __restrict__ b2, const float* __restrict__ tmp,
    char* __restrict__ WbfB, float* __restrict__ sbv,
    float* __restrict__ lraw, float* __restrict__ traw)
{
  __shared__ float pl[FEAT_];
  const int h = blockIdx.y;
  if (threadIdx.x < FEAT_) pl[threadIdx.x] = pvec[h * FEAT_ + threadIdx.x];
  __syncthreads();
  const int j4 = blockIdx.x * 1024 + threadIdx.x * 4;
  if (j4 >= P_) return;
  const float it = tmp[1];
  float4 acc = *reinterpret_cast<const float4*>(b2 + (size_t)h * P_ + j4);
  const float* __restrict__ wp = w2 + (size_t)h * FEAT_ * P_ + j4;
  #pragma unroll 4
  for (int k = 0; k < FEAT_; ++k) {
    const float pk = pl[k];
    const float4 wv = *reinterpret_cast<const float4*>(wp + (size_t)k * P_);
    acc.x = fmaf(pk, wv.x, acc.x);
    acc.y = fmaf(pk, wv.y, acc.y);
    acc.z = fmaf(pk, wv.z, acc.z);
    acc.w = fmaf(pk, wv.w, acc.w);
  }
  const float vals[4] = {acc.x, acc.y, acc.z, acc.w};
  if (j4 < SW_) {
    const int t = j4 / 3840, rem = j4 - t * 3840, i = rem >> 8, d = rem & 255;
    const int g = h * T_ + t;
    ushort4_t hs, ls;
    #pragma unroll
    for (int q = 0; q < 4; ++q) {
      const float v = tanhf(vals[q]) * 2.f * it;
      const unsigned short hb = f2bf(v);
      hs[q] = hb;
      ls[q] = f2bf(v - bf2f(hb));
    }
    const unsigned off = (unsigned)(i * 512 + d * 2) ^ ((unsigned)(i & 15) << 4);
    char* base = WbfB + (size_t)g * WGB_;
    *(ushort4_t*)(base + off) = hs;
    *(ushort4_t*)(base + 8192 + off) = ls;
  } else {
    #pragma unroll
    for (int q = 0; q < 4; ++q) {
      const int j = j4 + q;
      const float v = tanhf(vals[q]) * 2.f;
      if (j < SW_ + SB_)            sbv[h * SB_ + (j - SW_)] = v * it;
      else if (j < SW_ + SB_ + LF_) lraw[h * LF_ + (j - SW_ - SB_)] = v;
      else                          traw[h * T_ + (j - SW_ - SB_ - LF_)] = v;
    }
  }
}

// ---------------- head/tree softmax, scaled leaf probs + slA image + W pad-row zero ----------------
__global__ __launch_bounds__(256) void finalize_kernel(
    const float* __restrict__ head_weights, const float* __restrict__ traw,
    const float* __restrict__ lraw, const float* __restrict__ tmp,
    float* __restrict__ sl, char* __restrict__ slA, char* __restrict__ WbfB)
{
  __shared__ float hw[H_];
  __shared__ float wt[H_ * T_];
  const int tid = threadIdx.x;
  // zero pad row i=15 of each group's W image (both hi and lo halves)
  for (int idx = tid; idx < G_ * 128; idx += 256) {
    const int g = idx >> 7, w = idx & 127;
    char* base = WbfB + (size_t)g * WGB_ + 15 * 512 + w * 4;
    *(unsigned*)base = 0u;
    *(unsigned*)(base + 8192) = 0u;
  }
  if (tid == 0) {
    float m = -1e30f;
    for (int h = 0; h < H_; ++h) m = fmaxf(m, head_weights[h]);
    float s = 0.f, e[H_];
    for (int h = 0; h < H_; ++h) { e[h] = __expf(head_weights[h] - m); s += e[h]; }
    for (int h = 0; h < H_; ++h) hw[h] = e[h] / s;
  }
  __syncthreads();
  if (tid < H_ * T_) {
    const int h = tid / T_;
    float m = -1e30f;
    for (int t = 0; t < T_; ++t) m = fmaxf(m, traw[h * T_ + t]);
    float s = 0.f;
    for (int t = 0; t < T_; ++t) s += __expf(traw[h * T_ + t] - m);
    wt[tid] = hw[h] * __expf(traw[tid] - m) / s;
  }
  __syncthreads();
  const float it = tmp[1];
  for (int row = tid; row < H_ * T_ * L_; row += 256) {   // row = g*16 + l
    const int ht = row >> 4;
    const float* __restrict__ lr = lraw + (size_t)row * C_;
    float m = -1e30f;
    #pragma unroll
    for (int c = 0; c < C_; ++c) m = fmaxf(m, lr[c]);
    float e[C_]; float s = 0.f;
    #pragma unroll
    for (int c = 0; c < C_; ++c) { e[c] = __expf((lr[c] - m) * it); s += e[c]; }
    const float sc = wt[ht] / s;
    #pragma unroll
    for (int c = 0; c < C_; ++c) sl[(size_t)row * C_ + c] = e[c] * sc;
  }
  __syncthreads();
  // pack slA[g][lane]: A-fragment image for mfma_f32_16x16x32_bf16:
  // lane p: row c = p&15, k = (p>>4)*8 + j; value = sl[g*16 + l][c] for l=k<16 else 0
  for (int idx = tid; idx < G_ * 64; idx += 256) {
    const int g = idx >> 6, p = idx & 63;
    const int c = p & 15, kg = p >> 4;
    ushort4_t w0, w1;
    #pragma unroll
    for (int j = 0; j < 8; ++j) {
      const int l = kg * 8 + j;
      const unsigned short v = (l < 16 && c < 10) ? f2bf(sl[(size_t)(g * 16 + l) * C_ + c]) : (unsigned short)0;
      if (j < 4) w0[j] = v; else w1[j - 4] = v;
    }
    *(ushort4_t*)(slA + (size_t)idx * 16) = w0;
    *(ushort4_t*)(slA + (size_t)idx * 16 + 8) = w1;
  }
}

// ---------------- fused MFMA query kernel: 64 q/block, 4 waves x 16q, 2 blocks/CU ----------------
__global__ __launch_bounds__(256) void qk_kernel(
    const float* __restrict__ Xq, const char* __restrict__ WbfB,
    const char* __restrict__ slA, const float* __restrict__ sbv,
    float* __restrict__ out)
{
  __shared__ char lds[36864];       // [0,32768): W dbuf (2x16KB); [32768,36864): 4x1KB tw
  const int tid  = threadIdx.x;
  const int lane = tid & 63;
  const int wv   = tid >> 6;
  const int n0   = blockIdx.x * 64;
  const int lrow = lane & 15;       // A row (query) / B col (i) / leaf-A row (c)
  const int lkg  = lane >> 4;       // k-group 0..3

  // ---- build A-fragments for this wave's 16 queries (hi/lo bf16) ----
  short8 Ah[8], Al[8];
  {
    const float* xr = Xq + (size_t)(n0 + wv * 16 + lrow) * 256 + lkg * 8;
    #pragma unroll
    for (int ks = 0; ks < 8; ++ks) {
      const f32x4 a = *(const f32x4*)(xr + ks * 32);
      const f32x4 b = *(const f32x4*)(xr + ks * 32 + 4);
      short8 hh, ll;
      #pragma unroll
      for (int j = 0; j < 4; ++j) {
        unsigned short hb = f2bf(a[j]);
        hh[j] = (short)hb; ll[j] = (short)f2bf(a[j] - bf2f(hb));
        hb = f2bf(b[j]);
        hh[4 + j] = (short)hb; ll[4 + j] = (short)f2bf(b[j] - bf2f(hb));
      }
      Ah[ks] = hh; Al[ks] = ll;
    }
  }

  // ---- prologue: DMA group 0 into buf0 (each wave copies its 4KB segment) ----
  #pragma unroll
  for (int it = 0; it < 4; ++it) {
    const int seg = wv * 4096 + it * 1024;
    gload16(WbfB + seg + lane * 16, lds + seg);
  }
  __syncthreads();                  // drains vmcnt -> buf0 ready

  char* tw = lds + 32768 + wv * 1024;   // per-wave 16x16 f32 logit transpose
  const int q = lane & 15;              // query owned in the epilogue

  f32x4 Cac = {0.f, 0.f, 0.f, 0.f};

  int cur = 0;
  for (int g = 0; g < G_; ++g) {
    if (g + 1 < G_) {               // fire-and-forget DMA for next group
      const char* src = WbfB + (size_t)(g + 1) * WGB_;
      char* dst = lds + (cur ^ 1) * WGB_;
      #pragma unroll
      for (int it = 0; it < 4; ++it) {
        const int seg = wv * 4096 + it * 1024;
        gload16(src + seg + lane * 16, dst + seg);
      }
    }
    const short8 Asl = *(const short8*)(slA + (size_t)g * 1024 + lane * 16);
    float sbl[15];
    #pragma unroll
    for (int c = 0; c < 15; ++c) sbl[c] = sbv[g * 15 + c];

    const char* bb = lds + cur * WGB_;
    f32x4 Ch = {0,0,0,0}, Cm = {0,0,0,0};
    __builtin_amdgcn_s_setprio(1);
    #pragma unroll
    for (int ks = 0; ks < 8; ++ks) {
      const unsigned adr = (unsigned)(lrow * 512 + ks * 64 + lkg * 16) ^ ((unsigned)lrow << 4);
      const short8 bh = *(const short8*)(bb + adr);
      const short8 bl = *(const short8*)(bb + 8192 + adr);
      Ch = __builtin_amdgcn_mfma_f32_16x16x32_bf16(Ah[ks], bh, Ch, 0, 0, 0);
      Cm = __builtin_amdgcn_mfma_f32_16x16x32_bf16(Ah[ks], bl, Cm, 0, 0, 0);
      Cm = __builtin_amdgcn_mfma_f32_16x16x32_bf16(Al[ks], bh, Cm, 0, 0, 0);
    }
    __builtin_amdgcn_s_setprio(0);
    // transpose logits through per-wave LDS: lane holds D[q=lkg*4+j][i=lrow]
    {
      f32x4 cs;
      #pragma unroll
      for (int r = 0; r < 4; ++r) cs[r] = Ch[r] + Cm[r];
      const unsigned a = (unsigned)(lrow * 64) + ((unsigned)(lkg ^ (lrow & 3)) << 4);
      *(f32x4*)(tw + a) = cs;
    }
    // per-lane: 15 logits of query q (x4 duplicated) -> sigmoid -> full tree
    float dec[15];
    #pragma unroll
    for (int c = 0; c < 15; ++c) {
      const unsigned a = (unsigned)(c * 64) + ((unsigned)((q >> 2) ^ (c & 3)) << 4) + (unsigned)((q & 3) * 4);
      const float lg = *(const float*)(tw + a) + sbl[c];
      dec[c] = 1.f / (1.f + __expf(-lg));
    }
    float a_[2], b_[4], c_[8], r_[16];
    a_[0] = 1.f - dec[0]; a_[1] = dec[0];
    #pragma unroll
    for (int j = 0; j < 2; ++j) { b_[2*j] = a_[j] * (1.f - dec[1+j]); b_[2*j+1] = a_[j] * dec[1+j]; }
    #pragma unroll
    for (int j = 0; j < 4; ++j) { c_[2*j] = b_[j] * (1.f - dec[3+j]); c_[2*j+1] = b_[j] * dec[3+j]; }
    #pragma unroll
    for (int j = 0; j < 8; ++j) { r_[2*j] = c_[j] * (1.f - dec[7+j]); r_[2*j+1] = c_[j] * dec[7+j]; }
    // pack reach to bf16; lkg 0 supplies leaves 0..7, lkg 1 leaves 8..15, else 0
    const unsigned L0 = cvt_pk_bf16(r_[0],  r_[1]);
    const unsigned L1 = cvt_pk_bf16(r_[2],  r_[3]);
    const unsigned L2 = cvt_pk_bf16(r_[4],  r_[5]);
    const unsigned L3 = cvt_pk_bf16(r_[6],  r_[7]);
    const unsigned H0 = cvt_pk_bf16(r_[8],  r_[9]);
    const unsigned H1 = cvt_pk_bf16(r_[10], r_[11]);
    const unsigned H2 = cvt_pk_bf16(r_[12], r_[13]);
    const unsigned H3 = cvt_pk_bf16(r_[14], r_[15]);
    uint4_t bu;
    bu[0] = lkg == 0 ? L0 : (lkg == 1 ? H0 : 0u);
    bu[1] = lkg == 0 ? L1 : (lkg == 1 ? H1 : 0u);
    bu[2] = lkg == 0 ? L2 : (lkg == 1 ? H2 : 0u);
    bu[3] = lkg == 0 ? L3 : (lkg == 1 ? H3 : 0u);
    const short8 B0 = __builtin_bit_cast(short8, bu);
    Cac = __builtin_amdgcn_mfma_f32_16x16x32_bf16(Asl, B0, Cac, 0, 0, 0);
    __syncthreads();                // drains DMA (g+1 ready) + all reads of buf[cur] done
    cur ^= 1;
  }

  // store: D[c][q] col=lane&15=q, row c=lkg*4+j
  #pragma unroll
  for (int j = 0; j < 4; ++j) {
    const int c = lkg * 4 + j;
    if (c < 10) out[(size_t)(n0 + wv * 16 + q) * 10 + c] = Cac[j];
  }
}

// ---------------- diagnostic marker: only runs if a launch failed ----------------
__global__ void mark_kernel(float* out, float v) { out[threadIdx.x] = v; }

extern "C" void kernel_launch(void* const* d_in, const int* in_sizes, int n_in,
                              void* d_out, int out_size, void* d_ws, size_t ws_size,
                              hipStream_t stream) {
  (void)in_sizes; (void)n_in; (void)out_size;
  const float* Xs          = (const float*)d_in[0];
  const float* Xq          = (const float*)d_in[1];
  const float* enc_w1      = (const float*)d_in[2];
  const float* enc_b1      = (const float*)d_in[3];
  const float* ln1_g       = (const float*)d_in[4];
  const float* ln1_b       = (const float*)d_in[5];
  const float* enc_w2      = (const float*)d_in[6];
  const float* enc_b2      = (const float*)d_in[7];
  const float* ln2_g       = (const float*)d_in[8];
  const float* ln2_b       = (const float*)d_in[9];
  const float* pg_w1       = (const float*)d_in[10];
  const float* pg_b1       = (const float*)d_in[11];
  const float* pg_ln_g     = (const float*)d_in[12];
  const float* pg_ln_b     = (const float*)d_in[13];
  const float* pg_w2       = (const float*)d_in[14];
  const float* pg_b2       = (const float*)d_in[15];
  const float* head_wts    = (const float*)d_in[16];
  const float* temperature = (const float*)d_in[17];

  float* ws   = (float*)d_ws;
  float* h2   = ws + OFF_H2;
  float* pvec = ws + OFF_PVEC;
  float* tmp  = ws + OFF_TMP;
  float* sbp  = ws + OFF_SB;
  float* lrw  = ws + OFF_LRAW;
  float* trw  = ws + OFF_TRAW;
  float* slp  = ws + OFF_SL;
  char*  wbf  = (char*)(ws + OFF_WBF);
  char*  slA  = (char*)(ws + OFF_SLA);
  float* outp = (float*)d_out;

  unsigned mask = 0;
  (void)hipGetLastError();
  if (ws_size < WS_NEED_FLOATS * sizeof(float)) mask |= 0x80u;

  if (!mask) {
    enc12_kernel<<<dim3(128, 5), 256, 0, stream>>>(Xs, enc_w1, enc_b1, ln1_g, ln1_b,
                                                   enc_w2, enc_b2, ln2_g, ln2_b, h2);
    if (hipGetLastError() != hipSuccess) mask |= 1u;
    ctxpvec_kernel<<<5, 128, 0, stream>>>(h2, temperature, pg_w1, pg_b1, pg_ln_g, pg_ln_b, pvec, tmp);
    if (hipGetLastError() != hipSuccess) mask |= 2u;
    params_kernel<<<dim3(59, 5), 256, 0, stream>>>(pvec, pg_w2, pg_b2, tmp, wbf, sbp, lrw, trw);
    if (hipGetLastError() != hipSuccess) mask |= 4u;
    finalize_kernel<<<1, 256, 0, stream>>>(head_wts, trw, lrw, tmp, slp, slA, wbf);
    if (hipGetLastError() != hipSuccess) mask |= 8u;
    qk_kernel<<<NQ_ / 64, 256, 0, stream>>>(Xq, wbf, slA, sbp, outp);
    if (hipGetLastError() != hipSuccess) mask |= 16u;
  }
  if (mask) {
    mark_kernel<<<1, 16, 0, stream>>>(outp, 1024.f + 4.f * (float)mask);
    (void)hipGetLastError();
  }
}

// Round 8
// 252.173 us; speedup vs baseline: 1.9397x; 1.9397x over previous
//
#include <hip/hip_runtime.h>

#define DEV __device__ __forceinline__

typedef __attribute__((ext_vector_type(8))) short short8;
typedef __attribute__((ext_vector_type(4))) float f32x4;
typedef __attribute__((ext_vector_type(4))) unsigned short ushort4_t;
typedef __attribute__((ext_vector_type(4))) unsigned int uint4_t;

namespace {
constexpr int D_ = 256, C_ = 10, T_ = 15, H_ = 5, ENC_ = 64, L_ = 16;
constexpr int NS_ = 2048, NQ_ = 32768;
constexpr int P_ = 60240, SW_ = 57600, SB_ = 225, LF_ = 2400;
constexpr int FEAT_ = 128;
constexpr int G_ = 75;                      // H*T groups
constexpr int WGB_ = 16384;                 // bytes per group W-image
constexpr int NBLK_ = 128;                  // encoder blocks per head

// workspace layout (in floats)
constexpr size_t OFF_CP   = 0;                                  // 5*128*64 partial ctx sums
constexpr size_t OFF_PVEC = OFF_CP + (size_t)H_*NBLK_*ENC_;
constexpr size_t OFF_TMP  = OFF_PVEC + (size_t)H_*FEAT_;
constexpr size_t OFF_SB   = OFF_TMP + 8;
constexpr size_t OFF_LRAW = OFF_SB + (size_t)H_*T_*T_ + 16;
constexpr size_t OFF_TRAW = OFF_LRAW + (size_t)H_*T_*L_*C_;
constexpr size_t OFF_SL   = OFF_TRAW + (size_t)H_*T_;
constexpr size_t OFF_WBF  = OFF_SL + (size_t)H_*T_*L_*C_;       // 75*16384B
constexpr size_t OFF_SLA  = OFF_WBF + (size_t)G_*WGB_/4;        // 75*1024B
constexpr size_t WS_NEED_FLOATS = OFF_SLA + (size_t)G_*1024/4;
} // namespace

DEV float wave_sum(float v) {
  #pragma unroll
  for (int o = 32; o; o >>= 1) v += __shfl_xor(v, o, 64);
  return v;
}
DEV float gelu_exact(float x) { return 0.5f * x * (1.f + erff(x * 0.70710678118654752f)); }
DEV unsigned short f2bf(float x) {            // RNE bf16
  unsigned u = __float_as_uint(x);
  return (unsigned short)((u + 0x7FFFu + ((u >> 16) & 1u)) >> 16);
}
DEV float bf2f(unsigned short b) { return __uint_as_float(((unsigned)b) << 16); }
DEV unsigned cvt_pk_bf16(float lo, float hi) {
  unsigned d;
  asm("v_cvt_pk_bf16_f32 %0, %1, %2" : "=v"(d) : "v"(lo), "v"(hi));
  return d;
}
// async global -> LDS DMA, 16B per lane; lds dest = uniform base + lane*16
DEV void gload16(const char* g, char* l) {
  __builtin_amdgcn_global_load_lds(
      (const __attribute__((address_space(1))) void*)g,
      (__attribute__((address_space(3))) void*)l, 16, 0, 0);
}

// ---------------- fused encoder: enc2(enc1(X)) reduced in-block to ctx partials ----------------
__global__ __launch_bounds__(256) void enc12_kernel(
    const float* __restrict__ Xbase,
    const float* __restrict__ W1, const float* __restrict__ B1,
    const float* __restrict__ G1, const float* __restrict__ Be1,
    const float* __restrict__ W2, const float* __restrict__ B2,
    const float* __restrict__ G2, const float* __restrict__ Be2,
    float* __restrict__ Partial)
{
  __shared__ float xs[4][4][ENC_];     // [wave][row][col] = 4 KB
  __shared__ float red[4][ENC_];
  const int h = blockIdx.y;
  const int lane = threadIdx.x & 63;
  const int wv = threadIdx.x >> 6;
  const int row0 = blockIdx.x * 16 + wv * 4;

  { // ---- enc1: K=256 from global ----
    constexpr int K = 256;
    const float* __restrict__ X = Xbase + (size_t)row0 * K;
    const float* __restrict__ wc = W1 + (size_t)h * K * ENC_ + lane;
    float a0 = 0.f, a1 = 0.f, a2 = 0.f, a3 = 0.f;
    #pragma unroll 4
    for (int k = 0; k < K; ++k) {
      const float wkl = wc[(size_t)k * ENC_];
      a0 = fmaf(X[k],       wkl, a0);
      a1 = fmaf(X[K + k],   wkl, a1);
      a2 = fmaf(X[2*K + k], wkl, a2);
      a3 = fmaf(X[3*K + k], wkl, a3);
    }
    const float bb = B1[h*ENC_ + lane];
    const float gg = G1[h*ENC_ + lane], be = Be1[h*ENC_ + lane];
    float acc[4] = {a0 + bb, a1 + bb, a2 + bb, a3 + bb};
    #pragma unroll
    for (int r = 0; r < 4; ++r) {
      const float m = wave_sum(acc[r]) * (1.f / ENC_);
      const float d = acc[r] - m;
      const float var = wave_sum(d * d) * (1.f / ENC_);
      const float y = d * rsqrtf(var + 1e-5f) * gg + be;
      xs[wv][r][lane] = gelu_exact(y);
    }
  }
  __syncthreads();
  { // ---- enc2: K=64 from LDS (wave-local rows), then in-block ctx partial reduce ----
    constexpr int K = 64;
    const float* __restrict__ wc = W2 + (size_t)h * K * ENC_ + lane;
    float a0 = 0.f, a1 = 0.f, a2 = 0.f, a3 = 0.f;
    #pragma unroll 4
    for (int k = 0; k < K; ++k) {
      const float wkl = wc[(size_t)k * ENC_];
      a0 = fmaf(xs[wv][0][k], wkl, a0);
      a1 = fmaf(xs[wv][1][k], wkl, a1);
      a2 = fmaf(xs[wv][2][k], wkl, a2);
      a3 = fmaf(xs[wv][3][k], wkl, a3);
    }
    const float bb = B2[h*ENC_ + lane];
    const float gg = G2[h*ENC_ + lane], be = Be2[h*ENC_ + lane];
    float acc[4] = {a0 + bb, a1 + bb, a2 + bb, a3 + bb};
    float psum = 0.f;
    #pragma unroll
    for (int r = 0; r < 4; ++r) {
      const float m = wave_sum(acc[r]) * (1.f / ENC_);
      const float d = acc[r] - m;
      const float var = wave_sum(d * d) * (1.f / ENC_);
      const float y = d * rsqrtf(var + 1e-5f) * gg + be;
      psum += gelu_exact(y);
    }
    red[wv][lane] = psum;
    __syncthreads();
    if (wv == 0) {
      const float tot = red[0][lane] + red[1][lane] + red[2][lane] + red[3][lane];
      Partial[((size_t)h * NBLK_ + blockIdx.x) * ENC_ + lane] = tot;
    }
  }
}

// ---------------- reduce ctx partials + temperature + pvec, 128 threads/head ----------------
__global__ __launch_bounds__(128) void pvec_kernel(
    const float* __restrict__ Partial, const float* __restrict__ temperature,
    const float* __restrict__ w1, const float* __restrict__ b1,
    const float* __restrict__ g, const float* __restrict__ b,
    float* __restrict__ pvec, float* __restrict__ tmp)
{
  __shared__ float red[128];
  __shared__ float ctxl[ENC_];
  __shared__ float sred[2];
  const int h = blockIdx.x, tid = threadIdx.x;
  const int e = tid & 63, half = tid >> 6;
  float s = 0.f;
  const float* __restrict__ pp = Partial + (size_t)h * NBLK_ * ENC_ + e;
  #pragma unroll 4
  for (int bb = half * 64; bb < half * 64 + 64; ++bb) s += pp[(size_t)bb * ENC_];
  red[tid] = s;
  __syncthreads();
  if (half == 0) ctxl[e] = (red[e] + red[64 + e]) * (1.f / NS_);
  if (h == 0 && tid == 0) {
    const float t = fminf(fmaxf(temperature[0], 0.1f), 2.0f);
    tmp[0] = t; tmp[1] = 1.f / t;
  }
  __syncthreads();
  const int j = tid;
  float acc = b1[h * FEAT_ + j];
  #pragma unroll 4
  for (int e2 = 0; e2 < ENC_; ++e2)
    acc = fmaf(ctxl[e2], w1[((size_t)h * ENC_ + e2) * FEAT_ + j], acc);
  const int lane = j & 63, wvv = j >> 6;
  const float ps = wave_sum(acc);
  if (lane == 0) sred[wvv] = ps;
  __syncthreads();
  const float m = (sred[0] + sred[1]) * (1.f / FEAT_);
  const float d = acc - m;
  const float vs = wave_sum(d * d);
  __syncthreads();
  if (lane == 0) sred[wvv] = vs;
  __syncthreads();
  const float var = (sred[0] + sred[1]) * (1.f / FEAT_);
  const float y = d * rsqrtf(var + 1e-5f) * g[h * FEAT_ + j] + b[h * FEAT_ + j];
  pvec[h * FEAT_ + j] = gelu_exact(y);
}

// ---------------- params = tanh(p @ pg_w2 + pg_b2)*2 → W bf16 hi/lo image + sb/leaf/tree ----------------
__global__ __launch_bounds__(256) void params_kernel(
    const float* __restrict__ pvec, const float* __restrict__ w2,
    const float* __restrict__ b2, const float* __restrict__ tmp,
    char* __restrict__ WbfB, float* __restrict__ sbv,
    float* __restrict__ lraw, float* __restrict__ traw)
{
  __shared__ float pl[FEAT_];
  const int h = blockIdx.y;
  if (threadIdx.x < FEAT_) pl[threadIdx.x] = pvec[h * FEAT_ + threadIdx.x];
  __syncthreads();
  const int j4 = blockIdx.x * 1024 + threadIdx.x * 4;
  if (j4 >= P_) return;
  const float it = tmp[1];
  float4 acc = *reinterpret_cast<const float4*>(b2 + (size_t)h * P_ + j4);
  const float* __restrict__ wp = w2 + (size_t)h * FEAT_ * P_ + j4;
  #pragma unroll 4
  for (int k = 0; k < FEAT_; ++k) {
    const float pk = pl[k];
    const float4 wv = *reinterpret_cast<const float4*>(wp + (size_t)k * P_);
    acc.x = fmaf(pk, wv.x, acc.x);
    acc.y = fmaf(pk, wv.y, acc.y);
    acc.z = fmaf(pk, wv.z, acc.z);
    acc.w = fmaf(pk, wv.w, acc.w);
  }
  const float vals[4] = {acc.x, acc.y, acc.z, acc.w};
  if (j4 < SW_) {
    const int t = j4 / 3840, rem = j4 - t * 3840, i = rem >> 8, d = rem & 255;
    const int g = h * T_ + t;
    ushort4_t hs, ls;
    #pragma unroll
    for (int q = 0; q < 4; ++q) {
      const float v = tanhf(vals[q]) * 2.f * it;
      const unsigned short hb = f2bf(v);
      hs[q] = hb;
      ls[q] = f2bf(v - bf2f(hb));
    }
    const unsigned off = (unsigned)(i * 512 + d * 2) ^ ((unsigned)(i & 15) << 4);
    char* base = WbfB + (size_t)g * WGB_;
    *(ushort4_t*)(base + off) = hs;
    *(ushort4_t*)(base + 8192 + off) = ls;
  } else {
    #pragma unroll
    for (int q = 0; q < 4; ++q) {
      const int j = j4 + q;
      const float v = tanhf(vals[q]) * 2.f;
      if (j < SW_ + SB_)            sbv[h * SB_ + (j - SW_)] = v * it;
      else if (j < SW_ + SB_ + LF_) lraw[h * LF_ + (j - SW_ - SB_)] = v;
      else                          traw[h * T_ + (j - SW_ - SB_ - LF_)] = v;
    }
  }
}

// ---------------- head/tree softmax, scaled leaf probs + slA image + W pad-row zero ----------------
__global__ __launch_bounds__(256) void finalize_kernel(
    const float* __restrict__ head_weights, const float* __restrict__ traw,
    const float* __restrict__ lraw, const float* __restrict__ tmp,
    float* __restrict__ sl, char* __restrict__ slA, char* __restrict__ WbfB)
{
  __shared__ float hw[H_];
  __shared__ float wt[H_ * T_];
  const int tid = threadIdx.x;
  // zero pad row i=15 of each group's W image (both hi and lo halves)
  for (int idx = tid; idx < G_ * 128; idx += 256) {
    const int g = idx >> 7, w = idx & 127;
    char* base = WbfB + (size_t)g * WGB_ + 15 * 512 + w * 4;
    *(unsigned*)base = 0u;
    *(unsigned*)(base + 8192) = 0u;
  }
  if (tid == 0) {
    float m = -1e30f;
    for (int h = 0; h < H_; ++h) m = fmaxf(m, head_weights[h]);
    float s = 0.f, e[H_];
    for (int h = 0; h < H_; ++h) { e[h] = __expf(head_weights[h] - m); s += e[h]; }
    for (int h = 0; h < H_; ++h) hw[h] = e[h] / s;
  }
  __syncthreads();
  if (tid < H_ * T_) {
    const int h = tid / T_;
    float m = -1e30f;
    for (int t = 0; t < T_; ++t) m = fmaxf(m, traw[h * T_ + t]);
    float s = 0.f;
    for (int t = 0; t < T_; ++t) s += __expf(traw[h * T_ + t] - m);
    wt[tid] = hw[h] * __expf(traw[tid] - m) / s;
  }
  __syncthreads();
  const float it = tmp[1];
  for (int row = tid; row < H_ * T_ * L_; row += 256) {   // row = g*16 + l
    const int ht = row >> 4;
    const float* __restrict__ lr = lraw + (size_t)row * C_;
    float m = -1e30f;
    #pragma unroll
    for (int c = 0; c < C_; ++c) m = fmaxf(m, lr[c]);
    float e[C_]; float s = 0.f;
    #pragma unroll
    for (int c = 0; c < C_; ++c) { e[c] = __expf((lr[c] - m) * it); s += e[c]; }
    const float sc = wt[ht] / s;
    #pragma unroll
    for (int c = 0; c < C_; ++c) sl[(size_t)row * C_ + c] = e[c] * sc;
  }
  __syncthreads();
  // pack slA[g][lane]: A-fragment image for mfma_f32_16x16x32_bf16:
  // lane p: row c = p&15, k = (p>>4)*8 + j; value = sl[g*16 + l][c] for l=k<16 else 0
  for (int idx = tid; idx < G_ * 64; idx += 256) {
    const int g = idx >> 6, p = idx & 63;
    const int c = p & 15, kg = p >> 4;
    ushort4_t w0, w1;
    #pragma unroll
    for (int j = 0; j < 8; ++j) {
      const int l = kg * 8 + j;
      const unsigned short v = (l < 16 && c < 10) ? f2bf(sl[(size_t)(g * 16 + l) * C_ + c]) : (unsigned short)0;
      if (j < 4) w0[j] = v; else w1[j - 4] = v;
    }
    *(ushort4_t*)(slA + (size_t)idx * 16) = w0;
    *(ushort4_t*)(slA + (size_t)idx * 16 + 8) = w1;
  }
}

// ---------------- fused MFMA query kernel: 64 q/block, 4 waves x 16q, 2 blocks/CU ----------------
__global__ __launch_bounds__(256) void qk_kernel(
    const float* __restrict__ Xq, const char* __restrict__ WbfB,
    const char* __restrict__ slA, const float* __restrict__ sbv,
    float* __restrict__ out)
{
  __shared__ char lds[36864];       // [0,32768): W dbuf (2x16KB); [32768,36864): 4x1KB tw
  const int tid  = threadIdx.x;
  const int lane = tid & 63;
  const int wv   = tid >> 6;
  const int n0   = blockIdx.x * 64;
  const int lrow = lane & 15;       // A row (query) / B col (i) / leaf-A row (c)
  const int lkg  = lane >> 4;       // k-group 0..3

  // ---- build A-fragments for this wave's 16 queries (hi/lo bf16) ----
  short8 Ah[8], Al[8];
  {
    const float* xr = Xq + (size_t)(n0 + wv * 16 + lrow) * 256 + lkg * 8;
    #pragma unroll
    for (int ks = 0; ks < 8; ++ks) {
      const f32x4 a = *(const f32x4*)(xr + ks * 32);
      const f32x4 b = *(const f32x4*)(xr + ks * 32 + 4);
      short8 hh, ll;
      #pragma unroll
      for (int j = 0; j < 4; ++j) {
        unsigned short hb = f2bf(a[j]);
        hh[j] = (short)hb; ll[j] = (short)f2bf(a[j] - bf2f(hb));
        hb = f2bf(b[j]);
        hh[4 + j] = (short)hb; ll[4 + j] = (short)f2bf(b[j] - bf2f(hb));
      }
      Ah[ks] = hh; Al[ks] = ll;
    }
  }

  // ---- prologue: DMA group 0 into buf0 (each wave copies its 4KB segment) ----
  #pragma unroll
  for (int it = 0; it < 4; ++it) {
    const int seg = wv * 4096 + it * 1024;
    gload16(WbfB + seg + lane * 16, lds + seg);
  }
  __syncthreads();                  // drains vmcnt -> buf0 ready

  char* tw = lds + 32768 + wv * 1024;   // per-wave 16x16 f32 logit transpose
  const int q = lane & 15;              // query owned in the epilogue

  f32x4 Cac = {0.f, 0.f, 0.f, 0.f};

  int cur = 0;
  for (int g = 0; g < G_; ++g) {
    if (g + 1 < G_) {               // fire-and-forget DMA for next group
      const char* src = WbfB + (size_t)(g + 1) * WGB_;
      char* dst = lds + (cur ^ 1) * WGB_;
      #pragma unroll
      for (int it = 0; it < 4; ++it) {
        const int seg = wv * 4096 + it * 1024;
        gload16(src + seg + lane * 16, dst + seg);
      }
    }
    const short8 Asl = *(const short8*)(slA + (size_t)g * 1024 + lane * 16);
    float sbl[15];
    #pragma unroll
    for (int c = 0; c < 15; ++c) sbl[c] = sbv[g * 15 + c];

    const char* bb = lds + cur * WGB_;
    f32x4 Ch = {0,0,0,0}, Cm = {0,0,0,0};
    __builtin_amdgcn_s_setprio(1);
    #pragma unroll
    for (int ks = 0; ks < 8; ++ks) {
      const unsigned adr = (unsigned)(lrow * 512 + ks * 64 + lkg * 16) ^ ((unsigned)lrow << 4);
      const short8 bh = *(const short8*)(bb + adr);
      const short8 bl = *(const short8*)(bb + 8192 + adr);
      Ch = __builtin_amdgcn_mfma_f32_16x16x32_bf16(Ah[ks], bh, Ch, 0, 0, 0);
      Cm = __builtin_amdgcn_mfma_f32_16x16x32_bf16(Ah[ks], bl, Cm, 0, 0, 0);
      Cm = __builtin_amdgcn_mfma_f32_16x16x32_bf16(Al[ks], bh, Cm, 0, 0, 0);
    }
    __builtin_amdgcn_s_setprio(0);
    // transpose logits through per-wave LDS: lane holds D[q=lkg*4+j][i=lrow]
    {
      f32x4 cs;
      #pragma unroll
      for (int r = 0; r < 4; ++r) cs[r] = Ch[r] + Cm[r];
      const unsigned a = (unsigned)(lrow * 64) + ((unsigned)(lkg ^ (lrow & 3)) << 4);
      *(f32x4*)(tw + a) = cs;
    }
    // per-lane: 15 logits of query q (x4 duplicated) -> sigmoid -> full tree
    float dec[15];
    #pragma unroll
    for (int c = 0; c < 15; ++c) {
      const unsigned a = (unsigned)(c * 64) + ((unsigned)((q >> 2) ^ (c & 3)) << 4) + (unsigned)((q & 3) * 4);
      const float lg = *(const float*)(tw + a) + sbl[c];
      dec[c] = 1.f / (1.f + __expf(-lg));
    }
    float a_[2], b_[4], c_[8], r_[16];
    a_[0] = 1.f - dec[0]; a_[1] = dec[0];
    #pragma unroll
    for (int j = 0; j < 2; ++j) { b_[2*j] = a_[j] * (1.f - dec[1+j]); b_[2*j+1] = a_[j] * dec[1+j]; }
    #pragma unroll
    for (int j = 0; j < 4; ++j) { c_[2*j] = b_[j] * (1.f - dec[3+j]); c_[2*j+1] = b_[j] * dec[3+j]; }
    #pragma unroll
    for (int j = 0; j < 8; ++j) { r_[2*j] = c_[j] * (1.f - dec[7+j]); r_[2*j+1] = c_[j] * dec[7+j]; }
    // pack reach to bf16; lkg 0 supplies leaves 0..7, lkg 1 leaves 8..15, else 0
    const unsigned L0 = cvt_pk_bf16(r_[0],  r_[1]);
    const unsigned L1 = cvt_pk_bf16(r_[2],  r_[3]);
    const unsigned L2 = cvt_pk_bf16(r_[4],  r_[5]);
    const unsigned L3 = cvt_pk_bf16(r_[6],  r_[7]);
    const unsigned H0 = cvt_pk_bf16(r_[8],  r_[9]);
    const unsigned H1 = cvt_pk_bf16(r_[10], r_[11]);
    const unsigned H2 = cvt_pk_bf16(r_[12], r_[13]);
    const unsigned H3 = cvt_pk_bf16(r_[14], r_[15]);
    uint4_t bu;
    bu[0] = lkg == 0 ? L0 : (lkg == 1 ? H0 : 0u);
    bu[1] = lkg == 0 ? L1 : (lkg == 1 ? H1 : 0u);
    bu[2] = lkg == 0 ? L2 : (lkg == 1 ? H2 : 0u);
    bu[3] = lkg == 0 ? L3 : (lkg == 1 ? H3 : 0u);
    const short8 B0 = __builtin_bit_cast(short8, bu);
    Cac = __builtin_amdgcn_mfma_f32_16x16x32_bf16(Asl, B0, Cac, 0, 0, 0);
    __syncthreads();                // drains DMA (g+1 ready) + all reads of buf[cur] done
    cur ^= 1;
  }

  // store: D[c][q] col=lane&15=q, row c=lkg*4+j
  #pragma unroll
  for (int j = 0; j < 4; ++j) {
    const int c = lkg * 4 + j;
    if (c < 10) out[(size_t)(n0 + wv * 16 + q) * 10 + c] = Cac[j];
  }
}

// ---------------- diagnostic marker: only runs if a launch failed ----------------
__global__ void mark_kernel(float* out, float v) { out[threadIdx.x] = v; }

extern "C" void kernel_launch(void* const* d_in, const int* in_sizes, int n_in,
                              void* d_out, int out_size, void* d_ws, size_t ws_size,
                              hipStream_t stream) {
  (void)in_sizes; (void)n_in; (void)out_size;
  const float* Xs          = (const float*)d_in[0];
  const float* Xq          = (const float*)d_in[1];
  const float* enc_w1      = (const float*)d_in[2];
  const float* enc_b1      = (const float*)d_in[3];
  const float* ln1_g       = (const float*)d_in[4];
  const float* ln1_b       = (const float*)d_in[5];
  const float* enc_w2      = (const float*)d_in[6];
  const float* enc_b2      = (const float*)d_in[7];
  const float* ln2_g       = (const float*)d_in[8];
  const float* ln2_b       = (const float*)d_in[9];
  const float* pg_w1       = (const float*)d_in[10];
  const float* pg_b1       = (const float*)d_in[11];
  const float* pg_ln_g     = (const float*)d_in[12];
  const float* pg_ln_b     = (const float*)d_in[13];
  const float* pg_w2       = (const float*)d_in[14];
  const float* pg_b2       = (const float*)d_in[15];
  const float* head_wts    = (const float*)d_in[16];
  const float* temperature = (const float*)d_in[17];

  float* ws   = (float*)d_ws;
  float* cpart= ws + OFF_CP;
  float* pvec = ws + OFF_PVEC;
  float* tmp  = ws + OFF_TMP;
  float* sbp  = ws + OFF_SB;
  float* lrw  = ws + OFF_LRAW;
  float* trw  = ws + OFF_TRAW;
  float* slp  = ws + OFF_SL;
  char*  wbf  = (char*)(ws + OFF_WBF);
  char*  slA  = (char*)(ws + OFF_SLA);
  float* outp = (float*)d_out;

  unsigned mask = 0;
  (void)hipGetLastError();
  if (ws_size < WS_NEED_FLOATS * sizeof(float)) mask |= 0x80u;

  if (!mask) {
    enc12_kernel<<<dim3(NBLK_, 5), 256, 0, stream>>>(Xs, enc_w1, enc_b1, ln1_g, ln1_b,
                                                     enc_w2, enc_b2, ln2_g, ln2_b, cpart);
    if (hipGetLastError() != hipSuccess) mask |= 1u;
    pvec_kernel<<<5, 128, 0, stream>>>(cpart, temperature, pg_w1, pg_b1, pg_ln_g, pg_ln_b, pvec, tmp);
    if (hipGetLastError() != hipSuccess) mask |= 2u;
    params_kernel<<<dim3(59, 5), 256, 0, stream>>>(pvec, pg_w2, pg_b2, tmp, wbf, sbp, lrw, trw);
    if (hipGetLastError() != hipSuccess) mask |= 4u;
    finalize_kernel<<<1, 256, 0, stream>>>(head_wts, trw, lrw, tmp, slp, slA, wbf);
    if (hipGetLastError() != hipSuccess) mask |= 8u;
    qk_kernel<<<NQ_ / 64, 256, 0, stream>>>(Xq, wbf, slA, sbp, outp);
    if (hipGetLastError() != hipSuccess) mask |= 16u;
  }
  if (mask) {
    mark_kernel<<<1, 16, 0, stream>>>(outp, 1024.f + 4.f * (float)mask);
    (void)hipGetLastError();
  }
}